// Round 13
// baseline (189.277 us; speedup 1.0000x reference)
//
#include <hip/hip_runtime.h>
#include <hip/hip_fp16.h>

#define NN 50000
#define NE 800000

// bucket sort: bucket = dst >> 8 (256 dsts per bucket)
#define NBK 196                    // ceil(50000/256)
#define BSH 8
#define BMASK 255
#define SCAP 5120                  // >= max bucket population (mean 4082, +16 sigma)
#define CHUNK 2048                 // edges per sortA block
#define NBLK_A ((NE + CHUNK - 1) / CHUNK)   // 391
#define NBLK_P ((NN + 63) / 64)             // 782
#define GPAD 4                     // gcur stride = 16 ints = 64 B (1 line per counter)

typedef _Float16 f16x8 __attribute__((ext_vector_type(8)));
typedef float f32x4 __attribute__((ext_vector_type(4)));

// ---------------- K1: init gcur + convert/transpose weights ----------------
__global__ __launch_bounds__(256) void init_k(const float* __restrict__ W1,
                                              const float* __restrict__ W2,
                                              __half* __restrict__ w1t,
                                              __half* __restrict__ w2t,
                                              int* __restrict__ gcur) {
    const int i = blockIdx.x * 256 + threadIdx.x;   // 64 blocks = 16384 = 128*128
    {
        const int k = i >> 7, n = i & 127;
        w1t[n * 128 + k] = __float2half(W1[i]);
    }
    if (i < 128 * 64) {
        const int k = i >> 6, n = i & 63;
        w2t[n * 128 + k] = __float2half(W2[i]);
    }
    if (i < NBK) gcur[i << GPAD] = 0;
}

// ---------------- K2: fused sortA (bucket binning, flat flush) + proj1 (MFMA) ----------------
__global__ __launch_bounds__(256) void sortA_proj1_k(const int* __restrict__ src,
                                                     const int* __restrict__ dst,
                                                     const float* __restrict__ wE,
                                                     int* __restrict__ gcur,
                                                     int2* __restrict__ stage,
                                                     const float* __restrict__ x,
                                                     const __half* __restrict__ w1t,
                                                     const float* __restrict__ al1,
                                                     const float* __restrict__ ar1,
                                                     __half* __restrict__ h1h,
                                                     float* __restrict__ el1,
                                                     float* __restrict__ er1) {
    const int t = threadIdx.x;
    if (blockIdx.x < NBLK_A) {
        // ---- sortA ----
        __shared__ int hcnt[NBK], lexcl[NBK], lcur[NBK], gbase[NBK];
        __shared__ int wsum[4];
        __shared__ int2 lbuf[CHUNK];
        const int e0 = blockIdx.x * CHUNK;
        const int ne = min(CHUNK, NE - e0);
        if (t < NBK) { hcnt[t] = 0; lcur[t] = 0; }
        __syncthreads();
        for (int i = t; i < ne; i += 256) atomicAdd(&hcnt[dst[e0 + i] >> BSH], 1);
        __syncthreads();
        {
            const int lane = t & 63, wid = t >> 6;
            const int v = (t < NBK) ? hcnt[t] : 0;
            int s = v;
            #pragma unroll
            for (int off = 1; off < 64; off <<= 1) {
                int u = __shfl_up(s, off, 64);
                if (lane >= off) s += u;
            }
            if (lane == 63) wsum[wid] = s;
            __syncthreads();
            int add = 0;
            for (int w = 0; w < wid; w++) add += wsum[w];
            if (t < NBK) lexcl[t] = s - v + add;
        }
        __syncthreads();
        if (t < NBK && hcnt[t] > 0) gbase[t] = atomicAdd(&gcur[t << GPAD], hcnt[t]);
        __syncthreads();
        for (int i = t; i < ne; i += 256) {
            const int d = dst[e0 + i];
            const int b = d >> BSH;
            const int r = atomicAdd(&lcur[b], 1);
            lbuf[lexcl[b] + r] = make_int2((src[e0 + i] & 0xFFFF) | ((d & BMASK) << 16) | (b << 24),
                                           __float_as_int(wE[e0 + i]));
        }
        __syncthreads();
        for (int i = t; i < ne; i += 256) {
            const int2 v = lbuf[i];
            const int b = (unsigned int)v.x >> 24;
            const int pos = gbase[b] + (i - lexcl[b]);
            stage[(size_t)b * SCAP + pos] = v;
        }
    } else {
        // ---- proj1 (MFMA) ----
        const int bid = blockIdx.x - NBLK_A;
        const int l = t & 63, wv = t >> 6;
        const int rbase = bid * 64 + wv * 16;
        const int cl = l & 15, kg = l >> 4;
        const int arow = rbase + cl;
        const float* xrow = x + (size_t)(arow < NN ? arow : NN - 1) * 128;
        f16x8 afrag[4];
        #pragma unroll
        for (int ks = 0; ks < 4; ks++) {
            const float4 u0 = *(const float4*)(xrow + ks * 32 + kg * 8);
            const float4 u1 = *(const float4*)(xrow + ks * 32 + kg * 8 + 4);
            f16x8 a;
            a[0] = (_Float16)u0.x; a[1] = (_Float16)u0.y; a[2] = (_Float16)u0.z; a[3] = (_Float16)u0.w;
            a[4] = (_Float16)u1.x; a[5] = (_Float16)u1.y; a[6] = (_Float16)u1.z; a[7] = (_Float16)u1.w;
            afrag[ks] = a;
        }
        f32x4 acc[8];
        #pragma unroll
        for (int nt = 0; nt < 8; nt++) { acc[nt][0]=0.f; acc[nt][1]=0.f; acc[nt][2]=0.f; acc[nt][3]=0.f; }
        #pragma unroll
        for (int nt = 0; nt < 8; nt++) {
            const f16x8* bp = (const f16x8*)(w1t + (size_t)(nt * 16 + cl) * 128 + kg * 8);
            #pragma unroll
            for (int ks = 0; ks < 4; ks++)
                acc[nt] = __builtin_amdgcn_mfma_f32_16x16x32_f16(afrag[ks], bp[ks * 4], acc[nt], 0, 0, 0);
        }
        const int orow0 = rbase + kg * 4;
        #pragma unroll
        for (int nt = 0; nt < 8; nt++) {
            const int col = nt * 16 + cl;
            const float alc = al1[col], arc = ar1[col];
            #pragma unroll
            for (int r = 0; r < 4; r++) {
                const float v = acc[nt][r];
                const int orow = orow0 + r;
                const bool ok = (orow < NN);
                if (ok) h1h[(size_t)orow * 128 + col] = __float2half(v);
                float pe = v * alc, pr = v * arc;
                #pragma unroll
                for (int m = 1; m < 16; m <<= 1) {
                    pe += __shfl_xor(pe, m, 64);
                    pr += __shfl_xor(pr, m, 64);
                }
                if (ok && cl == 0) {
                    el1[(size_t)orow * 8 + nt] = pe;
                    er1[(size_t)orow * 8 + nt] = pr;
                }
            }
        }
    }
}

// ---------------- K3: sortB — histogram -> offs, scatter to csr, fused edge-softmax ----------------
// Per bucket: compute p[e][h]=exp(leaky(el1[src]+er1[dst])), z[n][h] via LDS atomics,
// write pw=p*w packed fp16 to pwh[e*8+h], z to zf[n*8+h].
__global__ __launch_bounds__(1024) void sortB_k(const int* __restrict__ gcur,
                                                const int2* __restrict__ stage,
                                                const float* __restrict__ el1,
                                                const float* __restrict__ er1,
                                                int* __restrict__ offs,
                                                unsigned int* __restrict__ csr,
                                                __half* __restrict__ pwh,
                                                float* __restrict__ zf) {
    __shared__ int cnt[256], cur[256], gall[NBK];
    __shared__ int wsum[4];
    __shared__ int sbase;
    __shared__ float erl[256][8];
    __shared__ float zacc[256][8];
    const int b = blockIdx.x, t = threadIdx.x;
    const int dlo = b << BSH;
    if (t < NBK) gall[t] = gcur[t << GPAD];
    if (t < 256) cnt[t] = 0;
    for (int i = t; i < 2048; i += 1024) {
        const int node = dlo + (i >> 3);
        erl[i >> 3][i & 7] = (node < NN) ? er1[(size_t)node * 8 + (i & 7)] : 0.f;
        zacc[i >> 3][i & 7] = 0.f;
    }
    __syncthreads();
    const int nb = gall[b];
    if (t < 64) {   // wave 0: base = sum gall[0..b)
        int part = 0;
        for (int i = t; i < b; i += 64) part += gall[i];
        #pragma unroll
        for (int m = 1; m < 64; m <<= 1) part += __shfl_xor(part, m, 64);
        if (t == 0) sbase = part;
    }
    const int2* sp = stage + (size_t)b * SCAP;
    for (int i = t; i < nb; i += 1024) atomicAdd(&cnt[(sp[i].x >> 16) & BMASK], 1);
    __syncthreads();
    const int base = sbase;
    {   // exclusive scan of cnt[0..256) by threads 0..255
        const int lane = t & 63, wid = t >> 6;
        const int v = (t < 256) ? cnt[t] : 0;
        int s = v;
        #pragma unroll
        for (int off = 1; off < 64; off <<= 1) {
            int u = __shfl_up(s, off, 64);
            if (lane >= off) s += u;
        }
        if (t < 256 && lane == 63) wsum[wid] = s;
        __syncthreads();
        if (t < 256) {
            int add = 0;
            for (int w = 0; w < wid; w++) add += wsum[w];
            const int excl = s - v + add;
            cur[t] = excl;
            if (dlo + t < NN) offs[dlo + t] = base + excl;
        }
        if (b == NBK - 1 && t == 0) offs[NN] = base + nb;
    }
    __syncthreads();
    for (int i = t; i < nb; i += 1024) {
        const int2 pr = sp[i];
        const int dloc = (pr.x >> 16) & BMASK;
        const int sv = pr.x & 0xFFFF;
        const float wf = __int_as_float(pr.y);
        const int r = atomicAdd(&cur[dloc], 1);
        const __half hw = __float2half(wf);
        csr[base + r] = (unsigned int)sv | ((unsigned int)__half_as_ushort(hw) << 16);
        // edge softmax numerators for 8 heads
        const float4 e0v = *(const float4*)(el1 + (size_t)sv * 8);
        const float4 e1v = *(const float4*)(el1 + (size_t)sv * 8 + 4);
        float elv[8];
        elv[0]=e0v.x; elv[1]=e0v.y; elv[2]=e0v.z; elv[3]=e0v.w;
        elv[4]=e1v.x; elv[5]=e1v.y; elv[6]=e1v.z; elv[7]=e1v.w;
        __half hv[8];
        #pragma unroll
        for (int h = 0; h < 8; h++) {
            float lg = elv[h] + erl[dloc][h];
            lg = lg > 0.f ? lg : 0.2f * lg;
            const float p = __expf(lg);
            atomicAdd(&zacc[dloc][h], p);
            hv[h] = __float2half(p * wf);
        }
        *(int4*)(pwh + (size_t)(base + r) * 8) = *(const int4*)hv;
    }
    __syncthreads();
    for (int i = t; i < 2048; i += 1024) {
        const int node = dlo + (i >> 3);
        if (node < NN) zf[(size_t)node * 8 + (i & 7)] = zacc[i >> 3][i & 7];
    }
}

// ---------------- K4: Layer 1 aggregation — pure gather+FMA (no logits, no shfl in loop) ----------------
// lane: g=l&15 (dim group, head hg=g>>1), es=l>>4; lane's edges E=es+4k (k=0..7) per 32-tile.
__global__ __launch_bounds__(128) void agg1_k(const int* __restrict__ offs,
                                              const unsigned int* __restrict__ csr,
                                              const __half* __restrict__ pwh,
                                              const float* __restrict__ zf,
                                              const __half* __restrict__ h1h,
                                              const float* __restrict__ b1,
                                              __half* __restrict__ h2in_h) {
    const int t = threadIdx.x, w = t >> 6, l = t & 63;
    const int n = blockIdx.x * 2 + w;
    const int beg = offs[n], deg = offs[n + 1] - beg;
    const int g = l & 15, es = l >> 4, hg = g >> 1;
    float acc[8];
    #pragma unroll
    for (int j = 0; j < 8; j++) acc[j] = 0.f;
    const float4* hp4 = (const float4*)h1h;

    for (int base = 0; base < deg; base += 32) {
        int sv[8];
        float pp[8];
        #pragma unroll
        for (int k = 0; k < 8; k++) {
            const int E = es + 4 * k;
            const bool ok = (base + E < deg);
            const int idx = beg + base + (ok ? E : 0);
            const unsigned int c = csr[idx];
            sv[k] = ok ? (int)(c & 0xFFFF) : 0;
            pp[k] = ok ? __half2float(pwh[(size_t)idx * 8 + hg]) : 0.f;
        }
        float4 vv[8];
        #pragma unroll
        for (int k = 0; k < 8; k++) vv[k] = hp4[(size_t)sv[k] * 16 + g];
        #pragma unroll
        for (int k = 0; k < 8; k++) {
            #pragma unroll
            for (int q = 0; q < 4; q++) {
                const float2 f = __half22float2(((const __half2*)&vv[k])[q]);
                acc[2 * q]     = fmaf(pp[k], f.x, acc[2 * q]);
                acc[2 * q + 1] = fmaf(pp[k], f.y, acc[2 * q + 1]);
            }
        }
    }
    // acc: reduce over es (bits 4,5)
    #pragma unroll
    for (int j = 0; j < 8; j++) {
        acc[j] += __shfl_xor(acc[j], 16, 64);
        acc[j] += __shfl_xor(acc[j], 32, 64);
    }
    if (l < 16) {
        const float z = zf[(size_t)n * 8 + hg];
        const float inv = (deg > 0) ? 1.f / z : 0.f;
        const float4* b4 = (const float4*)b1;
        const float4 bb0 = b4[g * 2], bb1 = b4[g * 2 + 1];
        __half hv[8];
        hv[0] = __float2half(fmaxf(acc[0] * inv + bb0.x, 0.f));
        hv[1] = __float2half(fmaxf(acc[1] * inv + bb0.y, 0.f));
        hv[2] = __float2half(fmaxf(acc[2] * inv + bb0.z, 0.f));
        hv[3] = __float2half(fmaxf(acc[3] * inv + bb0.w, 0.f));
        hv[4] = __float2half(fmaxf(acc[4] * inv + bb1.x, 0.f));
        hv[5] = __float2half(fmaxf(acc[5] * inv + bb1.y, 0.f));
        hv[6] = __float2half(fmaxf(acc[6] * inv + bb1.z, 0.f));
        hv[7] = __float2half(fmaxf(acc[7] * inv + bb1.w, 0.f));
        *(int4*)(h2in_h + (size_t)n * 128 + g * 8) = *(const int4*)hv;
    }
}

// ---------------- K5: Layer 2 projection (MFMA) ----------------
__global__ __launch_bounds__(256) void proj2_k(const __half* __restrict__ xh,
                                               const __half* __restrict__ w2t,
                                               const float* __restrict__ al2,
                                               const float* __restrict__ ar2,
                                               __half* __restrict__ h2h,
                                               float* __restrict__ el2,
                                               float* __restrict__ er2) {
    const int t = threadIdx.x, l = t & 63, wv = t >> 6;
    const int rbase = blockIdx.x * 64 + wv * 16;
    const int cl = l & 15, kg = l >> 4;
    const int arow = rbase + cl;
    const __half* xrow = xh + (size_t)(arow < NN ? arow : NN - 1) * 128;
    f16x8 afrag[4];
    #pragma unroll
    for (int ks = 0; ks < 4; ks++)
        afrag[ks] = *(const f16x8*)(xrow + ks * 32 + kg * 8);
    f32x4 acc[4];
    #pragma unroll
    for (int nt = 0; nt < 4; nt++) { acc[nt][0]=0.f; acc[nt][1]=0.f; acc[nt][2]=0.f; acc[nt][3]=0.f; }
    #pragma unroll
    for (int nt = 0; nt < 4; nt++) {
        const f16x8* bp = (const f16x8*)(w2t + (size_t)(nt * 16 + cl) * 128 + kg * 8);
        #pragma unroll
        for (int ks = 0; ks < 4; ks++)
            acc[nt] = __builtin_amdgcn_mfma_f32_16x16x32_f16(afrag[ks], bp[ks * 4], acc[nt], 0, 0, 0);
    }
    const int orow0 = rbase + kg * 4;
    float pe[4] = {0.f, 0.f, 0.f, 0.f}, pr[4] = {0.f, 0.f, 0.f, 0.f};
    #pragma unroll
    for (int nt = 0; nt < 4; nt++) {
        const int col = nt * 16 + cl;
        const float alc = al2[col], arc = ar2[col];
        #pragma unroll
        for (int r = 0; r < 4; r++) {
            const float v = acc[nt][r];
            const int orow = orow0 + r;
            if (orow < NN) h2h[(size_t)orow * 64 + col] = __float2half(v);
            pe[r] = fmaf(v, alc, pe[r]);
            pr[r] = fmaf(v, arc, pr[r]);
        }
    }
    #pragma unroll
    for (int r = 0; r < 4; r++) {
        #pragma unroll
        for (int m = 1; m < 16; m <<= 1) {
            pe[r] += __shfl_xor(pe[r], m, 64);
            pr[r] += __shfl_xor(pr[r], m, 64);
        }
        const int orow = orow0 + r;
        if (cl == 0 && orow < NN) { el2[orow] = pe[r]; er2[orow] = pr[r]; }
    }
}

// ---------------- K6: Layer 2 aggregation — 32-edge tiles, prefetch (unchanged) ----------------
__global__ __launch_bounds__(128) void agg2_k(const int* __restrict__ offs,
                                              const unsigned int* __restrict__ csr,
                                              const __half* __restrict__ h2h,
                                              const float* __restrict__ el2,
                                              const float* __restrict__ er2,
                                              const float* __restrict__ b2,
                                              float* __restrict__ out) {
    const int t = threadIdx.x, w = t >> 6, l = t & 63;
    const int n = blockIdx.x * 2 + w;
    const int beg = offs[n], deg = offs[n + 1] - beg;
    const int g = l & 7, es = l >> 3;
    const float erd = er2[n];
    float z_lane = 0.f;
    float acc[8];
    #pragma unroll
    for (int j = 0; j < 8; j++) acc[j] = 0.f;
    const float4* hp4 = (const float4*)h2h;

    int pr = 0;
    if (l < 32 && l < deg) pr = (int)csr[beg + l];
    for (int base = 0; base < deg; base += 32) {
        int prn = 0;
        const int nbase = base + 32;
        if (nbase < deg && l < 32 && nbase + l < deg) prn = (int)csr[beg + nbase + l];
        float pw = 0.f;
        if (l < 32 && base + l < deg) {
            const float v = el2[(unsigned int)pr & 0xFFFF] + erd;
            const float lg = v > 0.f ? v : 0.2f * v;
            const float p = __expf(lg);
            z_lane += p;
            pw = p * __half2float(__ushort_as_half((unsigned short)((unsigned int)pr >> 16)));
        }
        int sv[4];
        float pp[4];
        #pragma unroll
        for (int k = 0; k < 4; k++) {
            sv[k] = __shfl(pr, es + 8 * k, 64) & 0xFFFF;
            pp[k] = __shfl(pw, es + 8 * k, 64);
        }
        float4 vv[4];
        #pragma unroll
        for (int k = 0; k < 4; k++) vv[k] = hp4[(size_t)sv[k] * 8 + g];
        #pragma unroll
        for (int k = 0; k < 4; k++) {
            #pragma unroll
            for (int q = 0; q < 4; q++) {
                const float2 f = __half22float2(((const __half2*)&vv[k])[q]);
                acc[2 * q]     = fmaf(pp[k], f.x, acc[2 * q]);
                acc[2 * q + 1] = fmaf(pp[k], f.y, acc[2 * q + 1]);
            }
        }
        pr = prn;
    }
    z_lane += __shfl_xor(z_lane, 1, 64);
    z_lane += __shfl_xor(z_lane, 2, 64);
    z_lane += __shfl_xor(z_lane, 4, 64);
    z_lane += __shfl_xor(z_lane, 8, 64);
    z_lane += __shfl_xor(z_lane, 16, 64);
    z_lane += __shfl_xor(z_lane, 32, 64);
    #pragma unroll
    for (int j = 0; j < 8; j++) {
        acc[j] += __shfl_xor(acc[j], 8, 64);
        acc[j] += __shfl_xor(acc[j], 16, 64);
        acc[j] += __shfl_xor(acc[j], 32, 64);
    }
    if (l < 8) {
        const float inv = (deg > 0) ? 1.f / z_lane : 0.f;
        const float4* b4 = (const float4*)b2;
        const float4 bb0 = b4[g * 2], bb1 = b4[g * 2 + 1];
        float4 o0, o1;
        o0.x = acc[0] * inv + bb0.x;
        o0.y = acc[1] * inv + bb0.y;
        o0.z = acc[2] * inv + bb0.z;
        o0.w = acc[3] * inv + bb0.w;
        o1.x = acc[4] * inv + bb1.x;
        o1.y = acc[5] * inv + bb1.y;
        o1.z = acc[6] * inv + bb1.z;
        o1.w = acc[7] * inv + bb1.w;
        float4* op = (float4*)(out + (size_t)n * 64 + g * 8);
        op[0] = o0; op[1] = o1;
    }
}

// ---------------- host ----------------

extern "C" void kernel_launch(void* const* d_in, const int* in_sizes, int n_in,
                              void* d_out, int out_size, void* d_ws, size_t ws_size,
                              hipStream_t stream) {
    const float* feat = (const float*)d_in[0];
    const int*   srcv = (const int*)d_in[1];
    const int*   dstv = (const int*)d_in[2];
    const float* wE   = (const float*)d_in[3];
    const float* W1   = (const float*)d_in[4];
    const float* al1  = (const float*)d_in[5];
    const float* ar1  = (const float*)d_in[6];
    const float* b1   = (const float*)d_in[7];
    const float* W2   = (const float*)d_in[8];
    const float* al2  = (const float*)d_in[9];
    const float* ar2  = (const float*)d_in[10];
    const float* b2   = (const float*)d_in[11];
    float* out = (float*)d_out;

    char* ws = (char*)d_ws;
    size_t off = 0;
    auto take = [&](size_t bytes) -> char* {
        char* pp = ws + off;
        off = (off + bytes + 255) & ~(size_t)255;
        return pp;
    };
    __half* h1h   = (__half*)take((size_t)NN * 128 * 2);
    __half* h2h   = (__half*)take((size_t)NN * 64 * 2);
    __half* h2in_h= (__half*)take((size_t)NN * 128 * 2);   // 12.8 MB; first ~8 MB aliased as sort staging
    float* el1  = (float*)take((size_t)NN * 8 * 4);
    float* er1  = (float*)take((size_t)NN * 8 * 4);
    float* el2  = (float*)take((size_t)NN * 4);
    float* er2  = (float*)take((size_t)NN * 4);
    int* offs   = (int*)take((size_t)(NN + 1) * 4);
    unsigned int* csr = (unsigned int*)take((size_t)NE * 4);
    int* gcur   = (int*)take((size_t)(NBK << GPAD) * 4);
    __half* w1t = (__half*)take((size_t)128 * 128 * 2);
    __half* w2t = (__half*)take((size_t)64 * 128 * 2);
    __half* pwh = (__half*)take((size_t)NE * 8 * 2);       // 12.8 MB edge softmax numerators (x w)
    float* zf   = (float*)take((size_t)NN * 8 * 4);        // 1.6 MB per-node z
    int2* stage = (int2*)h2in_h;   // NBK*SCAP*8 = 8.03 MB, consumed (sortB) before agg1 writes h2in_h

    init_k<<<64, 256, 0, stream>>>(W1, W2, w1t, w2t, gcur);
    sortA_proj1_k<<<NBLK_A + NBLK_P, 256, 0, stream>>>(srcv, dstv, wE, gcur, stage,
                                                       feat, w1t, al1, ar1, h1h, el1, er1);
    sortB_k<<<NBK, 1024, 0, stream>>>(gcur, stage, el1, er1, offs, csr, pwh, zf);
    agg1_k<<<NN / 2, 128, 0, stream>>>(offs, csr, pwh, zf, h1h, b1, h2in_h);
    proj2_k<<<(NN + 63) / 64, 256, 0, stream>>>(h2in_h, w2t, al2, ar2, h2h, el2, er2);
    agg2_k<<<NN / 2, 128, 0, stream>>>(offs, csr, h2h, el2, er2, b2, out);
}

// Round 14
// 163.265 us; speedup vs baseline: 1.1593x; 1.1593x over previous
//
#include <hip/hip_runtime.h>
#include <hip/hip_fp16.h>

#define NN 50000
#define NE 800000

// bucket sort: bucket = dst >> 8 (256 dsts per bucket)
#define NBK 196                    // ceil(50000/256)
#define BSH 8
#define BMASK 255
#define SCAP 5120                  // >= max bucket population (mean 4082, +16 sigma)
#define CHUNK 2048                 // edges per sortA block
#define NBLK_A ((NE + CHUNK - 1) / CHUNK)   // 391
#define NBLK_P ((NN + 63) / 64)             // 782
#define GPAD 4                     // gcur stride = 16 ints = 64 B (1 line per counter)

typedef _Float16 f16x8 __attribute__((ext_vector_type(8)));
typedef float f32x4 __attribute__((ext_vector_type(4)));

__device__ __forceinline__ float h2f_hi(unsigned int u) {
    return __half2float(__ushort_as_half((unsigned short)(u >> 16)));
}

// ---------------- K1: init gcur + convert/transpose weights ----------------
__global__ __launch_bounds__(256) void init_k(const float* __restrict__ W1,
                                              const float* __restrict__ W2,
                                              __half* __restrict__ w1t,
                                              __half* __restrict__ w2t,
                                              int* __restrict__ gcur) {
    const int i = blockIdx.x * 256 + threadIdx.x;   // 64 blocks = 16384 = 128*128
    {
        const int k = i >> 7, n = i & 127;
        w1t[n * 128 + k] = __float2half(W1[i]);
    }
    if (i < 128 * 64) {
        const int k = i >> 6, n = i & 63;
        w2t[n * 128 + k] = __float2half(W2[i]);
    }
    if (i < NBK) gcur[i << GPAD] = 0;
}

// ---------------- K2: fused sortA (bucket binning, flat flush) + proj1 (MFMA) ----------------
__global__ __launch_bounds__(256) void sortA_proj1_k(const int* __restrict__ src,
                                                     const int* __restrict__ dst,
                                                     const float* __restrict__ wE,
                                                     int* __restrict__ gcur,
                                                     int2* __restrict__ stage,
                                                     const float* __restrict__ x,
                                                     const __half* __restrict__ w1t,
                                                     const float* __restrict__ al1,
                                                     const float* __restrict__ ar1,
                                                     __half* __restrict__ h1h,
                                                     float* __restrict__ el1,
                                                     float* __restrict__ er1) {
    const int t = threadIdx.x;
    if (blockIdx.x < NBLK_A) {
        // ---- sortA ----
        __shared__ int hcnt[NBK], lexcl[NBK], lcur[NBK], gbase[NBK];
        __shared__ int wsum[4];
        __shared__ int2 lbuf[CHUNK];
        const int e0 = blockIdx.x * CHUNK;
        const int ne = min(CHUNK, NE - e0);
        if (t < NBK) { hcnt[t] = 0; lcur[t] = 0; }
        __syncthreads();
        for (int i = t; i < ne; i += 256) atomicAdd(&hcnt[dst[e0 + i] >> BSH], 1);
        __syncthreads();
        {
            const int lane = t & 63, wid = t >> 6;
            const int v = (t < NBK) ? hcnt[t] : 0;
            int s = v;
            #pragma unroll
            for (int off = 1; off < 64; off <<= 1) {
                int u = __shfl_up(s, off, 64);
                if (lane >= off) s += u;
            }
            if (lane == 63) wsum[wid] = s;
            __syncthreads();
            int add = 0;
            for (int w = 0; w < wid; w++) add += wsum[w];
            if (t < NBK) lexcl[t] = s - v + add;
        }
        __syncthreads();
        if (t < NBK && hcnt[t] > 0) gbase[t] = atomicAdd(&gcur[t << GPAD], hcnt[t]);
        __syncthreads();
        for (int i = t; i < ne; i += 256) {
            const int d = dst[e0 + i];
            const int b = d >> BSH;
            const int r = atomicAdd(&lcur[b], 1);
            lbuf[lexcl[b] + r] = make_int2((src[e0 + i] & 0xFFFF) | ((d & BMASK) << 16) | (b << 24),
                                           __float_as_int(wE[e0 + i]));
        }
        __syncthreads();
        for (int i = t; i < ne; i += 256) {
            const int2 v = lbuf[i];
            const int b = (unsigned int)v.x >> 24;
            const int pos = gbase[b] + (i - lexcl[b]);
            stage[(size_t)b * SCAP + pos] = v;
        }
    } else {
        // ---- proj1 (MFMA) ----
        const int bid = blockIdx.x - NBLK_A;
        const int l = t & 63, wv = t >> 6;
        const int rbase = bid * 64 + wv * 16;
        const int cl = l & 15, kg = l >> 4;
        const int arow = rbase + cl;
        const float* xrow = x + (size_t)(arow < NN ? arow : NN - 1) * 128;
        f16x8 afrag[4];
        #pragma unroll
        for (int ks = 0; ks < 4; ks++) {
            const float4 u0 = *(const float4*)(xrow + ks * 32 + kg * 8);
            const float4 u1 = *(const float4*)(xrow + ks * 32 + kg * 8 + 4);
            f16x8 a;
            a[0] = (_Float16)u0.x; a[1] = (_Float16)u0.y; a[2] = (_Float16)u0.z; a[3] = (_Float16)u0.w;
            a[4] = (_Float16)u1.x; a[5] = (_Float16)u1.y; a[6] = (_Float16)u1.z; a[7] = (_Float16)u1.w;
            afrag[ks] = a;
        }
        f32x4 acc[8];
        #pragma unroll
        for (int nt = 0; nt < 8; nt++) { acc[nt][0]=0.f; acc[nt][1]=0.f; acc[nt][2]=0.f; acc[nt][3]=0.f; }
        #pragma unroll
        for (int nt = 0; nt < 8; nt++) {
            const f16x8* bp = (const f16x8*)(w1t + (size_t)(nt * 16 + cl) * 128 + kg * 8);
            #pragma unroll
            for (int ks = 0; ks < 4; ks++)
                acc[nt] = __builtin_amdgcn_mfma_f32_16x16x32_f16(afrag[ks], bp[ks * 4], acc[nt], 0, 0, 0);
        }
        const int orow0 = rbase + kg * 4;
        #pragma unroll
        for (int nt = 0; nt < 8; nt++) {
            const int col = nt * 16 + cl;
            const float alc = al1[col], arc = ar1[col];
            #pragma unroll
            for (int r = 0; r < 4; r++) {
                const float v = acc[nt][r];
                const int orow = orow0 + r;
                const bool ok = (orow < NN);
                if (ok) h1h[(size_t)orow * 128 + col] = __float2half(v);
                float pe = v * alc, pr = v * arc;
                #pragma unroll
                for (int m = 1; m < 16; m <<= 1) {
                    pe += __shfl_xor(pe, m, 64);
                    pr += __shfl_xor(pr, m, 64);
                }
                if (ok && cl == 0) {
                    el1[(size_t)orow * 8 + nt] = pe;
                    er1[(size_t)orow * 8 + nt] = pr;
                }
            }
        }
    }
}

// ---------------- K3: sortB — per-bucket histogram -> offs, scatter to csr ----------------
__global__ __launch_bounds__(1024) void sortB_k(const int* __restrict__ gcur,
                                                const int2* __restrict__ stage,
                                                int* __restrict__ offs,
                                                unsigned int* __restrict__ csr) {
    __shared__ int cnt[256], cur[256], gall[NBK];
    __shared__ int wsum[4];
    __shared__ int sbase;
    const int b = blockIdx.x, t = threadIdx.x;
    if (t < NBK) gall[t] = gcur[t << GPAD];
    if (t < 256) cnt[t] = 0;
    __syncthreads();
    const int nb = gall[b];
    if (t < 64) {   // wave 0: base = sum gall[0..b)
        int part = 0;
        for (int i = t; i < b; i += 64) part += gall[i];
        #pragma unroll
        for (int m = 1; m < 64; m <<= 1) part += __shfl_xor(part, m, 64);
        if (t == 0) sbase = part;
    }
    const int2* sp = stage + (size_t)b * SCAP;
    for (int i = t; i < nb; i += 1024) atomicAdd(&cnt[(sp[i].x >> 16) & BMASK], 1);
    __syncthreads();
    const int base = sbase;
    const int dlo = b << BSH;
    {   // exclusive scan of cnt[0..256) by threads 0..255
        const int lane = t & 63, wid = t >> 6;
        const int v = (t < 256) ? cnt[t] : 0;
        int s = v;
        #pragma unroll
        for (int off = 1; off < 64; off <<= 1) {
            int u = __shfl_up(s, off, 64);
            if (lane >= off) s += u;
        }
        if (t < 256 && lane == 63) wsum[wid] = s;
        __syncthreads();
        if (t < 256) {
            int add = 0;
            for (int w = 0; w < wid; w++) add += wsum[w];
            const int excl = s - v + add;
            cur[t] = excl;
            if (dlo + t < NN) offs[dlo + t] = base + excl;
        }
        if (b == NBK - 1 && t == 0) offs[NN] = base + nb;
    }
    __syncthreads();
    for (int i = t; i < nb; i += 1024) {
        const int2 pr = sp[i];
        const int dloc = (pr.x >> 16) & BMASK;
        const int sv = pr.x & 0xFFFF;
        const int r = atomicAdd(&cur[dloc], 1);
        const __half hw = __float2half(__int_as_float(pr.y));
        csr[base + r] = (unsigned int)sv | ((unsigned int)__half_as_ushort(hw) << 16);
    }
}

// ---------------- K4: Layer 1 aggregation — TWO nodes per wave, 16-edge tiles ----------------
// Node A edges in lanes 0-15 of pr, node B in lanes 16-31.
// logits: head h=l&7, edges e0=l>>3, e1=e0+8 (per node, all lanes participate).
// values: dim-group g=l&15 (head hg=g>>1), es=l>>4; per node edges es, es+4 (pw0), es+8, es+12 (pw1).
__global__ __launch_bounds__(128) void agg1_k(const int* __restrict__ offs,
                                              const unsigned int* __restrict__ csr,
                                              const __half* __restrict__ h1h,
                                              const float* __restrict__ el1,
                                              const float* __restrict__ er1,
                                              const float* __restrict__ b1,
                                              __half* __restrict__ h2in_h) {
    const int t = threadIdx.x, w = t >> 6, l = t & 63;
    const int nA = blockIdx.x * 4 + w * 2;
    const int nB = nA + 1;
    const int begA = offs[nA], degA = offs[nA + 1] - begA;
    const int begB = offs[nB], degB = offs[nB + 1] - begB;
    const int h = l & 7, e0 = l >> 3, e1 = e0 + 8;
    const int g = l & 15, es = l >> 4, hg = g >> 1;
    const float erA = er1[(size_t)nA * 8 + h];
    const float erB = er1[(size_t)nB * 8 + h];
    float zA = 0.f, zB = 0.f;
    float accA[8], accB[8];
    #pragma unroll
    for (int j = 0; j < 8; j++) { accA[j] = 0.f; accB[j] = 0.f; }
    const float4* hp4 = (const float4*)h1h;
    const int dmax = max(degA, degB);

    for (int base = 0; base < dmax; base += 16) {
        int pr = 0;
        if (l < 16) { if (base + l < degA) pr = (int)csr[begA + base + l]; }
        else if (l < 32) { const int e = l - 16; if (base + e < degB) pr = (int)csr[begB + base + e]; }
        // logits (each lane computes (e0,h),(e1,h) for BOTH nodes)
        const unsigned int pA0 = (unsigned int)__shfl(pr, e0, 64);
        const unsigned int pA1 = (unsigned int)__shfl(pr, e1, 64);
        const unsigned int pB0 = (unsigned int)__shfl(pr, 16 + e0, 64);
        const unsigned int pB1 = (unsigned int)__shfl(pr, 16 + e1, 64);
        float lgA0 = -1e30f, lgA1 = -1e30f, lgB0 = -1e30f, lgB1 = -1e30f;
        if (base + e0 < degA) { const float v = el1[(size_t)(pA0 & 0xFFFF) * 8 + h] + erA; lgA0 = v > 0.f ? v : 0.2f * v; }
        if (base + e1 < degA) { const float v = el1[(size_t)(pA1 & 0xFFFF) * 8 + h] + erA; lgA1 = v > 0.f ? v : 0.2f * v; }
        if (base + e0 < degB) { const float v = el1[(size_t)(pB0 & 0xFFFF) * 8 + h] + erB; lgB0 = v > 0.f ? v : 0.2f * v; }
        if (base + e1 < degB) { const float v = el1[(size_t)(pB1 & 0xFFFF) * 8 + h] + erB; lgB1 = v > 0.f ? v : 0.2f * v; }
        const float eA0 = __expf(lgA0), eA1 = __expf(lgA1);
        const float eB0 = __expf(lgB0), eB1 = __expf(lgB1);
        zA += eA0 + eA1;
        zB += eB0 + eB1;
        const float pwA0 = eA0 * h2f_hi(pA0), pwA1 = eA1 * h2f_hi(pA1);
        const float pwB0 = eB0 * h2f_hi(pB0), pwB1 = eB1 * h2f_hi(pB1);
        // values: node A edges es,es+4,es+8,es+12 ; node B same (+16 lane offset for pr)
        const int sA0 = __shfl(pr, es, 64) & 0xFFFF;
        const int sA1 = __shfl(pr, es + 4, 64) & 0xFFFF;
        const int sA2 = __shfl(pr, es + 8, 64) & 0xFFFF;
        const int sA3 = __shfl(pr, es + 12, 64) & 0xFFFF;
        const int sB0 = __shfl(pr, 16 + es, 64) & 0xFFFF;
        const int sB1 = __shfl(pr, 16 + es + 4, 64) & 0xFFFF;
        const int sB2 = __shfl(pr, 16 + es + 8, 64) & 0xFFFF;
        const int sB3 = __shfl(pr, 16 + es + 12, 64) & 0xFFFF;
        const float qA0 = __shfl(pwA0, es * 8 + hg, 64);
        const float qA1 = __shfl(pwA0, (es + 4) * 8 + hg, 64);
        const float qA2 = __shfl(pwA1, es * 8 + hg, 64);
        const float qA3 = __shfl(pwA1, (es + 4) * 8 + hg, 64);
        const float qB0 = __shfl(pwB0, es * 8 + hg, 64);
        const float qB1 = __shfl(pwB0, (es + 4) * 8 + hg, 64);
        const float qB2 = __shfl(pwB1, es * 8 + hg, 64);
        const float qB3 = __shfl(pwB1, (es + 4) * 8 + hg, 64);
        const float4 vA0 = hp4[(size_t)sA0 * 16 + g];
        const float4 vA1 = hp4[(size_t)sA1 * 16 + g];
        const float4 vA2 = hp4[(size_t)sA2 * 16 + g];
        const float4 vA3 = hp4[(size_t)sA3 * 16 + g];
        const float4 vB0 = hp4[(size_t)sB0 * 16 + g];
        const float4 vB1 = hp4[(size_t)sB1 * 16 + g];
        const float4 vB2 = hp4[(size_t)sB2 * 16 + g];
        const float4 vB3 = hp4[(size_t)sB3 * 16 + g];
        #pragma unroll
        for (int q = 0; q < 4; q++) {
            const float2 fA0 = __half22float2(((const __half2*)&vA0)[q]);
            const float2 fA1 = __half22float2(((const __half2*)&vA1)[q]);
            const float2 fA2 = __half22float2(((const __half2*)&vA2)[q]);
            const float2 fA3 = __half22float2(((const __half2*)&vA3)[q]);
            accA[2 * q]     = fmaf(qA0, fA0.x, fmaf(qA1, fA1.x, fmaf(qA2, fA2.x, fmaf(qA3, fA3.x, accA[2 * q]))));
            accA[2 * q + 1] = fmaf(qA0, fA0.y, fmaf(qA1, fA1.y, fmaf(qA2, fA2.y, fmaf(qA3, fA3.y, accA[2 * q + 1]))));
            const float2 fB0 = __half22float2(((const __half2*)&vB0)[q]);
            const float2 fB1 = __half22float2(((const __half2*)&vB1)[q]);
            const float2 fB2 = __half22float2(((const __half2*)&vB2)[q]);
            const float2 fB3 = __half22float2(((const __half2*)&vB3)[q]);
            accB[2 * q]     = fmaf(qB0, fB0.x, fmaf(qB1, fB1.x, fmaf(qB2, fB2.x, fmaf(qB3, fB3.x, accB[2 * q]))));
            accB[2 * q + 1] = fmaf(qB0, fB0.y, fmaf(qB1, fB1.y, fmaf(qB2, fB2.y, fmaf(qB3, fB3.y, accB[2 * q + 1]))));
        }
    }
    // z: reduce over edge-lanes (bits 3,4,5) -> every lane holds z for its h
    zA += __shfl_xor(zA, 8, 64);  zA += __shfl_xor(zA, 16, 64);  zA += __shfl_xor(zA, 32, 64);
    zB += __shfl_xor(zB, 8, 64);  zB += __shfl_xor(zB, 16, 64);  zB += __shfl_xor(zB, 32, 64);
    // acc: reduce over es (bits 4,5)
    #pragma unroll
    for (int j = 0; j < 8; j++) {
        accA[j] += __shfl_xor(accA[j], 16, 64);
        accA[j] += __shfl_xor(accA[j], 32, 64);
        accB[j] += __shfl_xor(accB[j], 16, 64);
        accB[j] += __shfl_xor(accB[j], 32, 64);
    }
    const float zgA = __shfl(zA, hg, 64);   // lane hg holds h=hg
    const float zgB = __shfl(zB, hg, 64);
    const float4* b4 = (const float4*)b1;
    const float4 bb0 = b4[g * 2], bb1 = b4[g * 2 + 1];
    if (l < 32) {
        const bool isA = (l < 16);
        const int n = isA ? nA : nB;
        const int deg = isA ? degA : degB;
        const float zg = isA ? zgA : zgB;
        const float* ac = isA ? accA : accB;
        const float inv = (deg > 0) ? 1.f / zg : 0.f;
        __half hv[8];
        hv[0] = __float2half(fmaxf(ac[0] * inv + bb0.x, 0.f));
        hv[1] = __float2half(fmaxf(ac[1] * inv + bb0.y, 0.f));
        hv[2] = __float2half(fmaxf(ac[2] * inv + bb0.z, 0.f));
        hv[3] = __float2half(fmaxf(ac[3] * inv + bb0.w, 0.f));
        hv[4] = __float2half(fmaxf(ac[4] * inv + bb1.x, 0.f));
        hv[5] = __float2half(fmaxf(ac[5] * inv + bb1.y, 0.f));
        hv[6] = __float2half(fmaxf(ac[6] * inv + bb1.z, 0.f));
        hv[7] = __float2half(fmaxf(ac[7] * inv + bb1.w, 0.f));
        *(int4*)(h2in_h + (size_t)n * 128 + g * 8) = *(const int4*)hv;
    }
}

// ---------------- K5: Layer 2 projection (MFMA) ----------------
__global__ __launch_bounds__(256) void proj2_k(const __half* __restrict__ xh,
                                               const __half* __restrict__ w2t,
                                               const float* __restrict__ al2,
                                               const float* __restrict__ ar2,
                                               __half* __restrict__ h2h,
                                               float* __restrict__ el2,
                                               float* __restrict__ er2) {
    const int t = threadIdx.x, l = t & 63, wv = t >> 6;
    const int rbase = blockIdx.x * 64 + wv * 16;
    const int cl = l & 15, kg = l >> 4;
    const int arow = rbase + cl;
    const __half* xrow = xh + (size_t)(arow < NN ? arow : NN - 1) * 128;
    f16x8 afrag[4];
    #pragma unroll
    for (int ks = 0; ks < 4; ks++)
        afrag[ks] = *(const f16x8*)(xrow + ks * 32 + kg * 8);
    f32x4 acc[4];
    #pragma unroll
    for (int nt = 0; nt < 4; nt++) { acc[nt][0]=0.f; acc[nt][1]=0.f; acc[nt][2]=0.f; acc[nt][3]=0.f; }
    #pragma unroll
    for (int nt = 0; nt < 4; nt++) {
        const f16x8* bp = (const f16x8*)(w2t + (size_t)(nt * 16 + cl) * 128 + kg * 8);
        #pragma unroll
        for (int ks = 0; ks < 4; ks++)
            acc[nt] = __builtin_amdgcn_mfma_f32_16x16x32_f16(afrag[ks], bp[ks * 4], acc[nt], 0, 0, 0);
    }
    const int orow0 = rbase + kg * 4;
    float pe[4] = {0.f, 0.f, 0.f, 0.f}, pr[4] = {0.f, 0.f, 0.f, 0.f};
    #pragma unroll
    for (int nt = 0; nt < 4; nt++) {
        const int col = nt * 16 + cl;
        const float alc = al2[col], arc = ar2[col];
        #pragma unroll
        for (int r = 0; r < 4; r++) {
            const float v = acc[nt][r];
            const int orow = orow0 + r;
            if (orow < NN) h2h[(size_t)orow * 64 + col] = __float2half(v);
            pe[r] = fmaf(v, alc, pe[r]);
            pr[r] = fmaf(v, arc, pr[r]);
        }
    }
    #pragma unroll
    for (int r = 0; r < 4; r++) {
        #pragma unroll
        for (int m = 1; m < 16; m <<= 1) {
            pe[r] += __shfl_xor(pe[r], m, 64);
            pr[r] += __shfl_xor(pr[r], m, 64);
        }
        const int orow = orow0 + r;
        if (cl == 0 && orow < NN) { el2[orow] = pe[r]; er2[orow] = pr[r]; }
    }
}

// ---------------- K6: Layer 2 aggregation — TWO nodes per wave, 16-edge tiles ----------------
// Node A edges in lanes 0-15 of pr, node B in 16-31. logits: lane l<16 -> A edge l; 16<=l<32 -> B edge l-16.
// values: g=l&7 (dim group), es=l>>3 (0..7); per node edges es, es+8.
__global__ __launch_bounds__(128) void agg2_k(const int* __restrict__ offs,
                                              const unsigned int* __restrict__ csr,
                                              const __half* __restrict__ h2h,
                                              const float* __restrict__ el2,
                                              const float* __restrict__ er2,
                                              const float* __restrict__ b2,
                                              float* __restrict__ out) {
    const int t = threadIdx.x, w = t >> 6, l = t & 63;
    const int nA = blockIdx.x * 4 + w * 2;
    const int nB = nA + 1;
    const int begA = offs[nA], degA = offs[nA + 1] - begA;
    const int begB = offs[nB], degB = offs[nB + 1] - begB;
    const int g = l & 7, es = l >> 3;
    const float erdA = er2[nA], erdB = er2[nB];
    float zl = 0.f;                 // lanes 0-15 accumulate A, 16-31 accumulate B
    float accA[8], accB[8];
    #pragma unroll
    for (int j = 0; j < 8; j++) { accA[j] = 0.f; accB[j] = 0.f; }
    const float4* hp4 = (const float4*)h2h;
    const int dmax = max(degA, degB);

    for (int base = 0; base < dmax; base += 16) {
        int pr = 0;
        bool okE = false;
        if (l < 16) { okE = (base + l < degA); if (okE) pr = (int)csr[begA + base + l]; }
        else if (l < 32) { const int e = l - 16; okE = (base + e < degB); if (okE) pr = (int)csr[begB + base + e]; }
        float pw = 0.f;
        if (okE) {
            const float er = (l < 16) ? erdA : erdB;
            const float v = el2[(unsigned int)pr & 0xFFFF] + er;
            const float lg = v > 0.f ? v : 0.2f * v;
            const float p = __expf(lg);
            zl += p;
            pw = p * h2f_hi((unsigned int)pr);
        }
        const int sA0 = __shfl(pr, es, 64) & 0xFFFF;
        const int sA1 = __shfl(pr, es + 8, 64) & 0xFFFF;
        const int sB0 = __shfl(pr, 16 + es, 64) & 0xFFFF;
        const int sB1 = __shfl(pr, 16 + es + 8, 64) & 0xFFFF;
        const float qA0 = __shfl(pw, es, 64);
        const float qA1 = __shfl(pw, es + 8, 64);
        const float qB0 = __shfl(pw, 16 + es, 64);
        const float qB1 = __shfl(pw, 16 + es + 8, 64);
        const float4 vA0 = hp4[(size_t)sA0 * 8 + g];
        const float4 vA1 = hp4[(size_t)sA1 * 8 + g];
        const float4 vB0 = hp4[(size_t)sB0 * 8 + g];
        const float4 vB1 = hp4[(size_t)sB1 * 8 + g];
        #pragma unroll
        for (int q = 0; q < 4; q++) {
            const float2 fA0 = __half22float2(((const __half2*)&vA0)[q]);
            const float2 fA1 = __half22float2(((const __half2*)&vA1)[q]);
            accA[2 * q]     = fmaf(qA0, fA0.x, fmaf(qA1, fA1.x, accA[2 * q]));
            accA[2 * q + 1] = fmaf(qA0, fA0.y, fmaf(qA1, fA1.y, accA[2 * q + 1]));
            const float2 fB0 = __half22float2(((const __half2*)&vB0)[q]);
            const float2 fB1 = __half22float2(((const __half2*)&vB1)[q]);
            accB[2 * q]     = fmaf(qB0, fB0.x, fmaf(qB1, fB1.x, accB[2 * q]));
            accB[2 * q + 1] = fmaf(qB0, fB0.y, fmaf(qB1, fB1.y, accB[2 * q + 1]));
        }
    }
    // z: reduce within 16-lane groups (bits 0-3); lanes 0-15 -> zA, 16-31 -> zB
    zl += __shfl_xor(zl, 1, 64);
    zl += __shfl_xor(zl, 2, 64);
    zl += __shfl_xor(zl, 4, 64);
    zl += __shfl_xor(zl, 8, 64);
    const float zA = __shfl(zl, 0, 64);
    const float zB = __shfl(zl, 16, 64);
    // acc: reduce over es (bits 3,4,5)
    #pragma unroll
    for (int j = 0; j < 8; j++) {
        accA[j] += __shfl_xor(accA[j], 8, 64);
        accA[j] += __shfl_xor(accA[j], 16, 64);
        accA[j] += __shfl_xor(accA[j], 32, 64);
        accB[j] += __shfl_xor(accB[j], 8, 64);
        accB[j] += __shfl_xor(accB[j], 16, 64);
        accB[j] += __shfl_xor(accB[j], 32, 64);
    }
    const float4* b4 = (const float4*)b2;
    const float4 bb0 = b4[g * 2], bb1 = b4[g * 2 + 1];
    if (l < 8 || (l >= 16 && l < 24)) {
        const bool isA = (l < 8);
        const int n = isA ? nA : nB;
        const int deg = isA ? degA : degB;
        const float z = isA ? zA : zB;
        const float* ac = isA ? accA : accB;
        const float inv = (deg > 0) ? 1.f / z : 0.f;
        float4 o0, o1;
        o0.x = ac[0] * inv + bb0.x;
        o0.y = ac[1] * inv + bb0.y;
        o0.z = ac[2] * inv + bb0.z;
        o0.w = ac[3] * inv + bb0.w;
        o1.x = ac[4] * inv + bb1.x;
        o1.y = ac[5] * inv + bb1.y;
        o1.z = ac[6] * inv + bb1.z;
        o1.w = ac[7] * inv + bb1.w;
        float4* op = (float4*)(out + (size_t)n * 64 + g * 8);
        op[0] = o0; op[1] = o1;
    }
}

// ---------------- host ----------------

extern "C" void kernel_launch(void* const* d_in, const int* in_sizes, int n_in,
                              void* d_out, int out_size, void* d_ws, size_t ws_size,
                              hipStream_t stream) {
    const float* feat = (const float*)d_in[0];
    const int*   srcv = (const int*)d_in[1];
    const int*   dstv = (const int*)d_in[2];
    const float* wE   = (const float*)d_in[3];
    const float* W1   = (const float*)d_in[4];
    const float* al1  = (const float*)d_in[5];
    const float* ar1  = (const float*)d_in[6];
    const float* b1   = (const float*)d_in[7];
    const float* W2   = (const float*)d_in[8];
    const float* al2  = (const float*)d_in[9];
    const float* ar2  = (const float*)d_in[10];
    const float* b2   = (const float*)d_in[11];
    float* out = (float*)d_out;

    char* ws = (char*)d_ws;
    size_t off = 0;
    auto take = [&](size_t bytes) -> char* {
        char* pp = ws + off;
        off = (off + bytes + 255) & ~(size_t)255;
        return pp;
    };
    __half* h1h   = (__half*)take((size_t)NN * 128 * 2);
    __half* h2h   = (__half*)take((size_t)NN * 64 * 2);
    __half* h2in_h= (__half*)take((size_t)NN * 128 * 2);   // 12.8 MB; first ~8 MB aliased as sort staging
    float* el1  = (float*)take((size_t)NN * 8 * 4);
    float* er1  = (float*)take((size_t)NN * 8 * 4);
    float* el2  = (float*)take((size_t)NN * 4);
    float* er2  = (float*)take((size_t)NN * 4);
    int* offs   = (int*)take((size_t)(NN + 1) * 4);
    unsigned int* csr = (unsigned int*)take((size_t)NE * 4);
    int* gcur   = (int*)take((size_t)(NBK << GPAD) * 4);
    __half* w1t = (__half*)take((size_t)128 * 128 * 2);
    __half* w2t = (__half*)take((size_t)64 * 128 * 2);
    int2* stage = (int2*)h2in_h;   // NBK*SCAP*8 = 8.03 MB, consumed (sortB) before agg1 writes h2in_h

    init_k<<<64, 256, 0, stream>>>(W1, W2, w1t, w2t, gcur);
    sortA_proj1_k<<<NBLK_A + NBLK_P, 256, 0, stream>>>(srcv, dstv, wE, gcur, stage,
                                                       feat, w1t, al1, ar1, h1h, el1, er1);
    sortB_k<<<NBK, 1024, 0, stream>>>(gcur, stage, offs, csr);
    agg1_k<<<NN / 4, 128, 0, stream>>>(offs, csr, h1h, el1, er1, b1, h2in_h);
    proj2_k<<<(NN + 63) / 64, 256, 0, stream>>>(h2in_h, w2t, al2, ar2, h2h, el2, er2);
    agg2_k<<<NN / 4, 128, 0, stream>>>(offs, csr, h2h, el2, er2, b2, out);
}

// Round 15
// 135.401 us; speedup vs baseline: 1.3979x; 1.2058x over previous
//
#include <hip/hip_runtime.h>
#include <hip/hip_fp16.h>

#define NN 50000
#define NE 800000

// bucket sort: bucket = dst >> 8 (256 dsts per bucket)
#define NBK 196                    // ceil(50000/256)
#define BSH 8
#define BMASK 255
#define SCAP 5120                  // >= max bucket population (mean 4082, +16 sigma)
#define CHUNK 2048                 // edges per sortA block
#define NBLK_A ((NE + CHUNK - 1) / CHUNK)   // 391
#define NBLK_P ((NN + 63) / 64)             // 782
#define GPAD 4                     // gcur stride = 16 ints = 64 B (1 line per counter)

typedef _Float16 f16x8 __attribute__((ext_vector_type(8)));
typedef float f32x4 __attribute__((ext_vector_type(4)));

__device__ __forceinline__ float h2f_hi(unsigned int u) {
    return __half2float(__ushort_as_half((unsigned short)(u >> 16)));
}

// ---------------- K1: init gcur + convert/transpose weights ----------------
__global__ __launch_bounds__(256) void init_k(const float* __restrict__ W1,
                                              const float* __restrict__ W2,
                                              __half* __restrict__ w1t,
                                              __half* __restrict__ w2t,
                                              int* __restrict__ gcur) {
    const int i = blockIdx.x * 256 + threadIdx.x;   // 64 blocks = 16384 = 128*128
    {
        const int k = i >> 7, n = i & 127;
        w1t[n * 128 + k] = __float2half(W1[i]);
    }
    if (i < 128 * 64) {
        const int k = i >> 6, n = i & 63;
        w2t[n * 128 + k] = __float2half(W2[i]);
    }
    if (i < NBK) gcur[i << GPAD] = 0;
}

// ---------------- K2: fused sortA (bucket binning, flat flush) + proj1 (MFMA) ----------------
__global__ __launch_bounds__(256) void sortA_proj1_k(const int* __restrict__ src,
                                                     const int* __restrict__ dst,
                                                     const float* __restrict__ wE,
                                                     int* __restrict__ gcur,
                                                     int2* __restrict__ stage,
                                                     const float* __restrict__ x,
                                                     const __half* __restrict__ w1t,
                                                     const float* __restrict__ al1,
                                                     const float* __restrict__ ar1,
                                                     __half* __restrict__ h1h,
                                                     float* __restrict__ el1,
                                                     float* __restrict__ er1) {
    const int t = threadIdx.x;
    if (blockIdx.x < NBLK_A) {
        // ---- sortA ----
        __shared__ int hcnt[NBK], lexcl[NBK], lcur[NBK], gbase[NBK];
        __shared__ int wsum[4];
        __shared__ int2 lbuf[CHUNK];
        const int e0 = blockIdx.x * CHUNK;
        const int ne = min(CHUNK, NE - e0);
        if (t < NBK) { hcnt[t] = 0; lcur[t] = 0; }
        __syncthreads();
        for (int i = t; i < ne; i += 256) atomicAdd(&hcnt[dst[e0 + i] >> BSH], 1);
        __syncthreads();
        {
            const int lane = t & 63, wid = t >> 6;
            const int v = (t < NBK) ? hcnt[t] : 0;
            int s = v;
            #pragma unroll
            for (int off = 1; off < 64; off <<= 1) {
                int u = __shfl_up(s, off, 64);
                if (lane >= off) s += u;
            }
            if (lane == 63) wsum[wid] = s;
            __syncthreads();
            int add = 0;
            for (int w = 0; w < wid; w++) add += wsum[w];
            if (t < NBK) lexcl[t] = s - v + add;
        }
        __syncthreads();
        if (t < NBK && hcnt[t] > 0) gbase[t] = atomicAdd(&gcur[t << GPAD], hcnt[t]);
        __syncthreads();
        for (int i = t; i < ne; i += 256) {
            const int d = dst[e0 + i];
            const int b = d >> BSH;
            const int r = atomicAdd(&lcur[b], 1);
            lbuf[lexcl[b] + r] = make_int2((src[e0 + i] & 0xFFFF) | ((d & BMASK) << 16) | (b << 24),
                                           __float_as_int(wE[e0 + i]));
        }
        __syncthreads();
        for (int i = t; i < ne; i += 256) {
            const int2 v = lbuf[i];
            const int b = (unsigned int)v.x >> 24;
            const int pos = gbase[b] + (i - lexcl[b]);
            stage[(size_t)b * SCAP + pos] = v;
        }
    } else {
        // ---- proj1 (MFMA) ----
        const int bid = blockIdx.x - NBLK_A;
        const int l = t & 63, wv = t >> 6;
        const int rbase = bid * 64 + wv * 16;
        const int cl = l & 15, kg = l >> 4;
        const int arow = rbase + cl;
        const float* xrow = x + (size_t)(arow < NN ? arow : NN - 1) * 128;
        f16x8 afrag[4];
        #pragma unroll
        for (int ks = 0; ks < 4; ks++) {
            const float4 u0 = *(const float4*)(xrow + ks * 32 + kg * 8);
            const float4 u1 = *(const float4*)(xrow + ks * 32 + kg * 8 + 4);
            f16x8 a;
            a[0] = (_Float16)u0.x; a[1] = (_Float16)u0.y; a[2] = (_Float16)u0.z; a[3] = (_Float16)u0.w;
            a[4] = (_Float16)u1.x; a[5] = (_Float16)u1.y; a[6] = (_Float16)u1.z; a[7] = (_Float16)u1.w;
            afrag[ks] = a;
        }
        f32x4 acc[8];
        #pragma unroll
        for (int nt = 0; nt < 8; nt++) { acc[nt][0]=0.f; acc[nt][1]=0.f; acc[nt][2]=0.f; acc[nt][3]=0.f; }
        #pragma unroll
        for (int nt = 0; nt < 8; nt++) {
            const f16x8* bp = (const f16x8*)(w1t + (size_t)(nt * 16 + cl) * 128 + kg * 8);
            #pragma unroll
            for (int ks = 0; ks < 4; ks++)
                acc[nt] = __builtin_amdgcn_mfma_f32_16x16x32_f16(afrag[ks], bp[ks * 4], acc[nt], 0, 0, 0);
        }
        const int orow0 = rbase + kg * 4;
        #pragma unroll
        for (int nt = 0; nt < 8; nt++) {
            const int col = nt * 16 + cl;
            const float alc = al1[col], arc = ar1[col];
            #pragma unroll
            for (int r = 0; r < 4; r++) {
                const float v = acc[nt][r];
                const int orow = orow0 + r;
                const bool ok = (orow < NN);
                if (ok) h1h[(size_t)orow * 128 + col] = __float2half(v);
                float pe = v * alc, pr = v * arc;
                #pragma unroll
                for (int m = 1; m < 16; m <<= 1) {
                    pe += __shfl_xor(pe, m, 64);
                    pr += __shfl_xor(pr, m, 64);
                }
                if (ok && cl == 0) {
                    el1[(size_t)orow * 8 + nt] = pe;
                    er1[(size_t)orow * 8 + nt] = pr;
                }
            }
        }
    }
}

// ---------------- K3: sortB — per-bucket histogram -> offs, scatter to csr ----------------
__global__ __launch_bounds__(1024) void sortB_k(const int* __restrict__ gcur,
                                                const int2* __restrict__ stage,
                                                int* __restrict__ offs,
                                                unsigned int* __restrict__ csr) {
    __shared__ int cnt[256], cur[256], gall[NBK];
    __shared__ int wsum[4];
    __shared__ int sbase;
    const int b = blockIdx.x, t = threadIdx.x;
    if (t < NBK) gall[t] = gcur[t << GPAD];
    if (t < 256) cnt[t] = 0;
    __syncthreads();
    const int nb = gall[b];
    if (t < 64) {   // wave 0: base = sum gall[0..b)
        int part = 0;
        for (int i = t; i < b; i += 64) part += gall[i];
        #pragma unroll
        for (int m = 1; m < 64; m <<= 1) part += __shfl_xor(part, m, 64);
        if (t == 0) sbase = part;
    }
    const int2* sp = stage + (size_t)b * SCAP;
    for (int i = t; i < nb; i += 1024) atomicAdd(&cnt[(sp[i].x >> 16) & BMASK], 1);
    __syncthreads();
    const int base = sbase;
    const int dlo = b << BSH;
    {   // exclusive scan of cnt[0..256) by threads 0..255
        const int lane = t & 63, wid = t >> 6;
        const int v = (t < 256) ? cnt[t] : 0;
        int s = v;
        #pragma unroll
        for (int off = 1; off < 64; off <<= 1) {
            int u = __shfl_up(s, off, 64);
            if (lane >= off) s += u;
        }
        if (t < 256 && lane == 63) wsum[wid] = s;
        __syncthreads();
        if (t < 256) {
            int add = 0;
            for (int w = 0; w < wid; w++) add += wsum[w];
            const int excl = s - v + add;
            cur[t] = excl;
            if (dlo + t < NN) offs[dlo + t] = base + excl;
        }
        if (b == NBK - 1 && t == 0) offs[NN] = base + nb;
    }
    __syncthreads();
    for (int i = t; i < nb; i += 1024) {
        const int2 pr = sp[i];
        const int dloc = (pr.x >> 16) & BMASK;
        const int sv = pr.x & 0xFFFF;
        const int r = atomicAdd(&cur[dloc], 1);
        const __half hw = __float2half(__int_as_float(pr.y));
        csr[base + r] = (unsigned int)sv | ((unsigned int)__half_as_ushort(hw) << 16);
    }
}

// ---------------- K4: Layer 1 aggregation — TWO nodes per wave, 16-edge tiles ----------------
// Node A edges in lanes 0-15 of pr, node B in lanes 16-31.
// logits: head h=l&7, edges e0=l>>3, e1=e0+8 (per node, all lanes participate).
// values: dim-group g=l&15 (head hg=g>>1), es=l>>4; per node edges es, es+4 (pw0), es+8, es+12 (pw1).
__global__ __launch_bounds__(128) void agg1_k(const int* __restrict__ offs,
                                              const unsigned int* __restrict__ csr,
                                              const __half* __restrict__ h1h,
                                              const float* __restrict__ el1,
                                              const float* __restrict__ er1,
                                              const float* __restrict__ b1,
                                              __half* __restrict__ h2in_h) {
    const int t = threadIdx.x, w = t >> 6, l = t & 63;
    const int nA = blockIdx.x * 4 + w * 2;
    const int nB = nA + 1;
    const int begA = offs[nA], degA = offs[nA + 1] - begA;
    const int begB = offs[nB], degB = offs[nB + 1] - begB;
    const int h = l & 7, e0 = l >> 3, e1 = e0 + 8;
    const int g = l & 15, es = l >> 4, hg = g >> 1;
    const float erA = er1[(size_t)nA * 8 + h];
    const float erB = er1[(size_t)nB * 8 + h];
    float zA = 0.f, zB = 0.f;
    float accA[8], accB[8];
    #pragma unroll
    for (int j = 0; j < 8; j++) { accA[j] = 0.f; accB[j] = 0.f; }
    const float4* hp4 = (const float4*)h1h;
    const int dmax = max(degA, degB);

    for (int base = 0; base < dmax; base += 16) {
        int pr = 0;
        if (l < 16) { if (base + l < degA) pr = (int)csr[begA + base + l]; }
        else if (l < 32) { const int e = l - 16; if (base + e < degB) pr = (int)csr[begB + base + e]; }
        // logits (each lane computes (e0,h),(e1,h) for BOTH nodes)
        const unsigned int pA0 = (unsigned int)__shfl(pr, e0, 64);
        const unsigned int pA1 = (unsigned int)__shfl(pr, e1, 64);
        const unsigned int pB0 = (unsigned int)__shfl(pr, 16 + e0, 64);
        const unsigned int pB1 = (unsigned int)__shfl(pr, 16 + e1, 64);
        float lgA0 = -1e30f, lgA1 = -1e30f, lgB0 = -1e30f, lgB1 = -1e30f;
        if (base + e0 < degA) { const float v = el1[(size_t)(pA0 & 0xFFFF) * 8 + h] + erA; lgA0 = v > 0.f ? v : 0.2f * v; }
        if (base + e1 < degA) { const float v = el1[(size_t)(pA1 & 0xFFFF) * 8 + h] + erA; lgA1 = v > 0.f ? v : 0.2f * v; }
        if (base + e0 < degB) { const float v = el1[(size_t)(pB0 & 0xFFFF) * 8 + h] + erB; lgB0 = v > 0.f ? v : 0.2f * v; }
        if (base + e1 < degB) { const float v = el1[(size_t)(pB1 & 0xFFFF) * 8 + h] + erB; lgB1 = v > 0.f ? v : 0.2f * v; }
        const float eA0 = __expf(lgA0), eA1 = __expf(lgA1);
        const float eB0 = __expf(lgB0), eB1 = __expf(lgB1);
        zA += eA0 + eA1;
        zB += eB0 + eB1;
        const float pwA0 = eA0 * h2f_hi(pA0), pwA1 = eA1 * h2f_hi(pA1);
        const float pwB0 = eB0 * h2f_hi(pB0), pwB1 = eB1 * h2f_hi(pB1);
        // values: node A edges es,es+4,es+8,es+12 ; node B same (+16 lane offset for pr)
        const int sA0 = __shfl(pr, es, 64) & 0xFFFF;
        const int sA1 = __shfl(pr, es + 4, 64) & 0xFFFF;
        const int sA2 = __shfl(pr, es + 8, 64) & 0xFFFF;
        const int sA3 = __shfl(pr, es + 12, 64) & 0xFFFF;
        const int sB0 = __shfl(pr, 16 + es, 64) & 0xFFFF;
        const int sB1 = __shfl(pr, 16 + es + 4, 64) & 0xFFFF;
        const int sB2 = __shfl(pr, 16 + es + 8, 64) & 0xFFFF;
        const int sB3 = __shfl(pr, 16 + es + 12, 64) & 0xFFFF;
        const float qA0 = __shfl(pwA0, es * 8 + hg, 64);
        const float qA1 = __shfl(pwA0, (es + 4) * 8 + hg, 64);
        const float qA2 = __shfl(pwA1, es * 8 + hg, 64);
        const float qA3 = __shfl(pwA1, (es + 4) * 8 + hg, 64);
        const float qB0 = __shfl(pwB0, es * 8 + hg, 64);
        const float qB1 = __shfl(pwB0, (es + 4) * 8 + hg, 64);
        const float qB2 = __shfl(pwB1, es * 8 + hg, 64);
        const float qB3 = __shfl(pwB1, (es + 4) * 8 + hg, 64);
        const float4 vA0 = hp4[(size_t)sA0 * 16 + g];
        const float4 vA1 = hp4[(size_t)sA1 * 16 + g];
        const float4 vA2 = hp4[(size_t)sA2 * 16 + g];
        const float4 vA3 = hp4[(size_t)sA3 * 16 + g];
        const float4 vB0 = hp4[(size_t)sB0 * 16 + g];
        const float4 vB1 = hp4[(size_t)sB1 * 16 + g];
        const float4 vB2 = hp4[(size_t)sB2 * 16 + g];
        const float4 vB3 = hp4[(size_t)sB3 * 16 + g];
        #pragma unroll
        for (int q = 0; q < 4; q++) {
            const float2 fA0 = __half22float2(((const __half2*)&vA0)[q]);
            const float2 fA1 = __half22float2(((const __half2*)&vA1)[q]);
            const float2 fA2 = __half22float2(((const __half2*)&vA2)[q]);
            const float2 fA3 = __half22float2(((const __half2*)&vA3)[q]);
            accA[2 * q]     = fmaf(qA0, fA0.x, fmaf(qA1, fA1.x, fmaf(qA2, fA2.x, fmaf(qA3, fA3.x, accA[2 * q]))));
            accA[2 * q + 1] = fmaf(qA0, fA0.y, fmaf(qA1, fA1.y, fmaf(qA2, fA2.y, fmaf(qA3, fA3.y, accA[2 * q + 1]))));
            const float2 fB0 = __half22float2(((const __half2*)&vB0)[q]);
            const float2 fB1 = __half22float2(((const __half2*)&vB1)[q]);
            const float2 fB2 = __half22float2(((const __half2*)&vB2)[q]);
            const float2 fB3 = __half22float2(((const __half2*)&vB3)[q]);
            accB[2 * q]     = fmaf(qB0, fB0.x, fmaf(qB1, fB1.x, fmaf(qB2, fB2.x, fmaf(qB3, fB3.x, accB[2 * q]))));
            accB[2 * q + 1] = fmaf(qB0, fB0.y, fmaf(qB1, fB1.y, fmaf(qB2, fB2.y, fmaf(qB3, fB3.y, accB[2 * q + 1]))));
        }
    }
    // z: reduce over edge-lanes (bits 3,4,5) -> every lane holds z for its h
    zA += __shfl_xor(zA, 8, 64);  zA += __shfl_xor(zA, 16, 64);  zA += __shfl_xor(zA, 32, 64);
    zB += __shfl_xor(zB, 8, 64);  zB += __shfl_xor(zB, 16, 64);  zB += __shfl_xor(zB, 32, 64);
    // acc: reduce over es (bits 4,5)
    #pragma unroll
    for (int j = 0; j < 8; j++) {
        accA[j] += __shfl_xor(accA[j], 16, 64);
        accA[j] += __shfl_xor(accA[j], 32, 64);
        accB[j] += __shfl_xor(accB[j], 16, 64);
        accB[j] += __shfl_xor(accB[j], 32, 64);
    }
    const float zgA = __shfl(zA, hg, 64);   // lane hg holds h=hg
    const float zgB = __shfl(zB, hg, 64);
    const float4* b4 = (const float4*)b1;
    const float4 bb0 = b4[g * 2], bb1 = b4[g * 2 + 1];
    if (l < 32) {
        const bool isA = (l < 16);
        const int n = isA ? nA : nB;
        const int deg = isA ? degA : degB;
        const float zg = isA ? zgA : zgB;
        const float inv = (deg > 0) ? 1.f / zg : 0.f;
        // per-element static-index select (NO pointer to register arrays -> stays in VGPRs)
        float ac[8];
        #pragma unroll
        for (int j = 0; j < 8; j++) ac[j] = isA ? accA[j] : accB[j];
        __half hv[8];
        hv[0] = __float2half(fmaxf(ac[0] * inv + bb0.x, 0.f));
        hv[1] = __float2half(fmaxf(ac[1] * inv + bb0.y, 0.f));
        hv[2] = __float2half(fmaxf(ac[2] * inv + bb0.z, 0.f));
        hv[3] = __float2half(fmaxf(ac[3] * inv + bb0.w, 0.f));
        hv[4] = __float2half(fmaxf(ac[4] * inv + bb1.x, 0.f));
        hv[5] = __float2half(fmaxf(ac[5] * inv + bb1.y, 0.f));
        hv[6] = __float2half(fmaxf(ac[6] * inv + bb1.z, 0.f));
        hv[7] = __float2half(fmaxf(ac[7] * inv + bb1.w, 0.f));
        *(int4*)(h2in_h + (size_t)n * 128 + g * 8) = *(const int4*)hv;
    }
}

// ---------------- K5: Layer 2 projection (MFMA) ----------------
__global__ __launch_bounds__(256) void proj2_k(const __half* __restrict__ xh,
                                               const __half* __restrict__ w2t,
                                               const float* __restrict__ al2,
                                               const float* __restrict__ ar2,
                                               __half* __restrict__ h2h,
                                               float* __restrict__ el2,
                                               float* __restrict__ er2) {
    const int t = threadIdx.x, l = t & 63, wv = t >> 6;
    const int rbase = blockIdx.x * 64 + wv * 16;
    const int cl = l & 15, kg = l >> 4;
    const int arow = rbase + cl;
    const __half* xrow = xh + (size_t)(arow < NN ? arow : NN - 1) * 128;
    f16x8 afrag[4];
    #pragma unroll
    for (int ks = 0; ks < 4; ks++)
        afrag[ks] = *(const f16x8*)(xrow + ks * 32 + kg * 8);
    f32x4 acc[4];
    #pragma unroll
    for (int nt = 0; nt < 4; nt++) { acc[nt][0]=0.f; acc[nt][1]=0.f; acc[nt][2]=0.f; acc[nt][3]=0.f; }
    #pragma unroll
    for (int nt = 0; nt < 4; nt++) {
        const f16x8* bp = (const f16x8*)(w2t + (size_t)(nt * 16 + cl) * 128 + kg * 8);
        #pragma unroll
        for (int ks = 0; ks < 4; ks++)
            acc[nt] = __builtin_amdgcn_mfma_f32_16x16x32_f16(afrag[ks], bp[ks * 4], acc[nt], 0, 0, 0);
    }
    const int orow0 = rbase + kg * 4;
    float pe[4] = {0.f, 0.f, 0.f, 0.f}, pr[4] = {0.f, 0.f, 0.f, 0.f};
    #pragma unroll
    for (int nt = 0; nt < 4; nt++) {
        const int col = nt * 16 + cl;
        const float alc = al2[col], arc = ar2[col];
        #pragma unroll
        for (int r = 0; r < 4; r++) {
            const float v = acc[nt][r];
            const int orow = orow0 + r;
            if (orow < NN) h2h[(size_t)orow * 64 + col] = __float2half(v);
            pe[r] = fmaf(v, alc, pe[r]);
            pr[r] = fmaf(v, arc, pr[r]);
        }
    }
    #pragma unroll
    for (int r = 0; r < 4; r++) {
        #pragma unroll
        for (int m = 1; m < 16; m <<= 1) {
            pe[r] += __shfl_xor(pe[r], m, 64);
            pr[r] += __shfl_xor(pr[r], m, 64);
        }
        const int orow = orow0 + r;
        if (cl == 0 && orow < NN) { el2[orow] = pe[r]; er2[orow] = pr[r]; }
    }
}

// ---------------- K6: Layer 2 aggregation — TWO nodes per wave, 16-edge tiles ----------------
__global__ __launch_bounds__(128) void agg2_k(const int* __restrict__ offs,
                                              const unsigned int* __restrict__ csr,
                                              const __half* __restrict__ h2h,
                                              const float* __restrict__ el2,
                                              const float* __restrict__ er2,
                                              const float* __restrict__ b2,
                                              float* __restrict__ out) {
    const int t = threadIdx.x, w = t >> 6, l = t & 63;
    const int nA = blockIdx.x * 4 + w * 2;
    const int nB = nA + 1;
    const int begA = offs[nA], degA = offs[nA + 1] - begA;
    const int begB = offs[nB], degB = offs[nB + 1] - begB;
    const int g = l & 7, es = l >> 3;
    const float erdA = er2[nA], erdB = er2[nB];
    float zl = 0.f;                 // lanes 0-15 accumulate A, 16-31 accumulate B
    float accA[8], accB[8];
    #pragma unroll
    for (int j = 0; j < 8; j++) { accA[j] = 0.f; accB[j] = 0.f; }
    const float4* hp4 = (const float4*)h2h;
    const int dmax = max(degA, degB);

    for (int base = 0; base < dmax; base += 16) {
        int pr = 0;
        bool okE = false;
        if (l < 16) { okE = (base + l < degA); if (okE) pr = (int)csr[begA + base + l]; }
        else if (l < 32) { const int e = l - 16; okE = (base + e < degB); if (okE) pr = (int)csr[begB + base + e]; }
        float pw = 0.f;
        if (okE) {
            const float er = (l < 16) ? erdA : erdB;
            const float v = el2[(unsigned int)pr & 0xFFFF] + er;
            const float lg = v > 0.f ? v : 0.2f * v;
            const float p = __expf(lg);
            zl += p;
            pw = p * h2f_hi((unsigned int)pr);
        }
        const int sA0 = __shfl(pr, es, 64) & 0xFFFF;
        const int sA1 = __shfl(pr, es + 8, 64) & 0xFFFF;
        const int sB0 = __shfl(pr, 16 + es, 64) & 0xFFFF;
        const int sB1 = __shfl(pr, 16 + es + 8, 64) & 0xFFFF;
        const float qA0 = __shfl(pw, es, 64);
        const float qA1 = __shfl(pw, es + 8, 64);
        const float qB0 = __shfl(pw, 16 + es, 64);
        const float qB1 = __shfl(pw, 16 + es + 8, 64);
        const float4 vA0 = hp4[(size_t)sA0 * 8 + g];
        const float4 vA1 = hp4[(size_t)sA1 * 8 + g];
        const float4 vB0 = hp4[(size_t)sB0 * 8 + g];
        const float4 vB1 = hp4[(size_t)sB1 * 8 + g];
        #pragma unroll
        for (int q = 0; q < 4; q++) {
            const float2 fA0 = __half22float2(((const __half2*)&vA0)[q]);
            const float2 fA1 = __half22float2(((const __half2*)&vA1)[q]);
            accA[2 * q]     = fmaf(qA0, fA0.x, fmaf(qA1, fA1.x, accA[2 * q]));
            accA[2 * q + 1] = fmaf(qA0, fA0.y, fmaf(qA1, fA1.y, accA[2 * q + 1]));
            const float2 fB0 = __half22float2(((const __half2*)&vB0)[q]);
            const float2 fB1 = __half22float2(((const __half2*)&vB1)[q]);
            accB[2 * q]     = fmaf(qB0, fB0.x, fmaf(qB1, fB1.x, accB[2 * q]));
            accB[2 * q + 1] = fmaf(qB0, fB0.y, fmaf(qB1, fB1.y, accB[2 * q + 1]));
        }
    }
    // z: reduce within 16-lane groups (bits 0-3); lanes 0-15 -> zA, 16-31 -> zB
    zl += __shfl_xor(zl, 1, 64);
    zl += __shfl_xor(zl, 2, 64);
    zl += __shfl_xor(zl, 4, 64);
    zl += __shfl_xor(zl, 8, 64);
    const float zA = __shfl(zl, 0, 64);
    const float zB = __shfl(zl, 16, 64);
    // acc: reduce over es (bits 3,4,5)
    #pragma unroll
    for (int j = 0; j < 8; j++) {
        accA[j] += __shfl_xor(accA[j], 8, 64);
        accA[j] += __shfl_xor(accA[j], 16, 64);
        accA[j] += __shfl_xor(accA[j], 32, 64);
        accB[j] += __shfl_xor(accB[j], 8, 64);
        accB[j] += __shfl_xor(accB[j], 16, 64);
        accB[j] += __shfl_xor(accB[j], 32, 64);
    }
    const float4* b4 = (const float4*)b2;
    const float4 bb0 = b4[g * 2], bb1 = b4[g * 2 + 1];
    if (l < 8 || (l >= 16 && l < 24)) {
        const bool isA = (l < 8);
        const int n = isA ? nA : nB;
        const int deg = isA ? degA : degB;
        const float z = isA ? zA : zB;
        const float inv = (deg > 0) ? 1.f / z : 0.f;
        // per-element static-index select (NO pointer to register arrays -> stays in VGPRs)
        float ac[8];
        #pragma unroll
        for (int j = 0; j < 8; j++) ac[j] = isA ? accA[j] : accB[j];
        float4 o0, o1;
        o0.x = ac[0] * inv + bb0.x;
        o0.y = ac[1] * inv + bb0.y;
        o0.z = ac[2] * inv + bb0.z;
        o0.w = ac[3] * inv + bb0.w;
        o1.x = ac[4] * inv + bb1.x;
        o1.y = ac[5] * inv + bb1.y;
        o1.z = ac[6] * inv + bb1.z;
        o1.w = ac[7] * inv + bb1.w;
        float4* op = (float4*)(out + (size_t)n * 64 + g * 8);
        op[0] = o0; op[1] = o1;
    }
}

// ---------------- host ----------------

extern "C" void kernel_launch(void* const* d_in, const int* in_sizes, int n_in,
                              void* d_out, int out_size, void* d_ws, size_t ws_size,
                              hipStream_t stream) {
    const float* feat = (const float*)d_in[0];
    const int*   srcv = (const int*)d_in[1];
    const int*   dstv = (const int*)d_in[2];
    const float* wE   = (const float*)d_in[3];
    const float* W1   = (const float*)d_in[4];
    const float* al1  = (const float*)d_in[5];
    const float* ar1  = (const float*)d_in[6];
    const float* b1   = (const float*)d_in[7];
    const float* W2   = (const float*)d_in[8];
    const float* al2  = (const float*)d_in[9];
    const float* ar2  = (const float*)d_in[10];
    const float* b2   = (const float*)d_in[11];
    float* out = (float*)d_out;

    char* ws = (char*)d_ws;
    size_t off = 0;
    auto take = [&](size_t bytes) -> char* {
        char* pp = ws + off;
        off = (off + bytes + 255) & ~(size_t)255;
        return pp;
    };
    __half* h1h   = (__half*)take((size_t)NN * 128 * 2);
    __half* h2h   = (__half*)take((size_t)NN * 64 * 2);
    __half* h2in_h= (__half*)take((size_t)NN * 128 * 2);   // 12.8 MB; first ~8 MB aliased as sort staging
    float* el1  = (float*)take((size_t)NN * 8 * 4);
    float* er1  = (float*)take((size_t)NN * 8 * 4);
    float* el2  = (float*)take((size_t)NN * 4);
    float* er2  = (float*)take((size_t)NN * 4);
    int* offs   = (int*)take((size_t)(NN + 1) * 4);
    unsigned int* csr = (unsigned int*)take((size_t)NE * 4);
    int* gcur   = (int*)take((size_t)(NBK << GPAD) * 4);
    __half* w1t = (__half*)take((size_t)128 * 128 * 2);
    __half* w2t = (__half*)take((size_t)64 * 128 * 2);
    int2* stage = (int2*)h2in_h;   // NBK*SCAP*8 = 8.03 MB, consumed (sortB) before agg1 writes h2in_h

    init_k<<<64, 256, 0, stream>>>(W1, W2, w1t, w2t, gcur);
    sortA_proj1_k<<<NBLK_A + NBLK_P, 256, 0, stream>>>(srcv, dstv, wE, gcur, stage,
                                                       feat, w1t, al1, ar1, h1h, el1, er1);
    sortB_k<<<NBK, 1024, 0, stream>>>(gcur, stage, offs, csr);
    agg1_k<<<NN / 4, 128, 0, stream>>>(offs, csr, h1h, el1, er1, b1, h2in_h);
    proj2_k<<<(NN + 63) / 64, 256, 0, stream>>>(h2in_h, w2t, al2, ar2, h2h, el2, er2);
    agg2_k<<<NN / 4, 128, 0, stream>>>(offs, csr, h2h, el2, er2, b2, out);
}